// Round 2
// baseline (705.678 us; speedup 1.0000x reference)
//
#include <hip/hip_runtime.h>
#include <cstdint>

typedef float f32x4 __attribute__((ext_vector_type(4)));
typedef short bf16x8 __attribute__((ext_vector_type(8)));

#define QP_BASE 0
#define KP_BASE 16384
#define VT_BASE 32768
#define P_BASE  49152

__device__ __forceinline__ unsigned short f2bf(float f){
  union { float f; uint32_t u; } v; v.f = f;
  uint32_t u = v.u;
  return (unsigned short)((u + 0x7FFFu + ((u >> 16) & 1u)) >> 16);  // RNE
}
__device__ __forceinline__ float bf2f(unsigned short h){
  union { uint32_t u; float f; } v; v.u = ((uint32_t)h) << 16;
  return v.f;
}
__device__ __forceinline__ f32x4 mfma16x16x32(bf16x8 a, bf16x8 b, f32x4 c){
  return __builtin_amdgcn_mfma_f32_16x16x32_bf16(a, b, c, 0, 0, 0);
}
__device__ __forceinline__ void gload_lds16(const void* gsrc, void* ldst){
  __builtin_amdgcn_global_load_lds(
    (const __attribute__((address_space(1))) unsigned int*)gsrc,
    (__attribute__((address_space(3))) unsigned int*)ldst, 16, 0, 0);
}

// ---------------- prep: weights -> bf16 [N][K] (optionally swizzled), w_o hi/lo, bias expand ----
// wsu layout (shorts): WT_q [0,16384) | WT_v [16384,32768) | WT_k [32768,65536)
//                      WT_oh [65536,81920) | WT_ol [81920,98304) | bias_exp f32 [98304,163840)
__global__ void prep_kernel(const float* __restrict__ wq, const float* __restrict__ wk,
                            const float* __restrict__ wv, const float* __restrict__ wo,
                            const float* __restrict__ btab, unsigned short* __restrict__ wsu,
                            int swz)
{
  const int idx = blockIdx.x * 256 + threadIdx.x;
  if (idx < 16384){                          // WT_q[n][k] = wq[k][n]
    const int n = idx >> 7, k = idx & 127;
    const int kk2 = swz ? (k ^ ((n & 7) << 3)) : k;
    wsu[n*128 + kk2] = f2bf(wq[k*128 + n]);
  } else if (idx < 32768){                   // WT_v
    const int i = idx - 16384, n = i >> 7, k = i & 127;
    const int kk2 = swz ? (k ^ ((n & 7) << 3)) : k;
    wsu[16384 + n*128 + kk2] = f2bf(wv[k*128 + n]);
  } else if (idx < 65536){                   // WT_k (K=256)
    const int i = idx - 32768, n = i >> 8, k = i & 255;
    const int kk2 = swz ? (k ^ ((n & 7) << 3)) : k;
    wsu[32768 + n*256 + kk2] = f2bf(wk[k*128 + n]);
  } else if (idx < 81920){                   // WT_o hi/lo (always linear)
    const int i = idx - 65536, n = i >> 7, k = i & 127;
    const float f = wo[k*128 + n];
    const unsigned short hv = f2bf(f);
    wsu[65536 + n*128 + k] = hv;
    wsu[81920 + n*128 + k] = f2bf(f - bf2f(hv));
  } else if (idx < 114688){                  // bias_exp[h][q][k]
    const int i = idx - 81920;
    const int h = i >> 12, q = (i >> 6) & 63, kx = i & 63;
    const int qi = q >> 3, qj = q & 7, ki = kx >> 3, kj = kx & 7;
    const int rel = (qi - ki + 7) * 15 + (qj - kj + 7);
    reinterpret_cast<float*>(wsu + 98304)[i] = btab[rel*8 + h];
  }
}

// =================== K1: projection GEMMs -> ws (pre-swizzled per-window chunks) ===========
// qs/ks chunk (16KB/window): byte = (row<<8) + ((ch<<1) ^ ((row&7)<<4))
// vs chunk (16KB/window):    byte = (h<<11) + (c16<<7) + ((key<<1) ^ ((c16&7)<<4))
template<int KC, bool VT>
__device__ __forceinline__ void proj_one(const float* __restrict__ X, const float* __restrict__ bias,
    const char* wlds, char* outstage, long winbase, int wave, int lane, int g, int c16)
{
  constexpr int NKS = KC / 32;
  constexpr int SH  = (KC == 128) ? 8 : 9;
  const int rA = 16*wave + c16;
  const float* xrow = X + (winbase + (long)(rA >> 3) * 256 + (rA & 7)) * KC;
  bf16x8 a[NKS];
#pragma unroll
  for (int ks = 0; ks < NKS; ++ks){
    const float4* p = reinterpret_cast<const float4*>(xrow + 32*ks + 8*g);
    const float4 x0 = p[0], x1 = p[1];
    bf16x8 t;
    t[0]=(short)f2bf(x0.x); t[1]=(short)f2bf(x0.y); t[2]=(short)f2bf(x0.z); t[3]=(short)f2bf(x0.w);
    t[4]=(short)f2bf(x1.x); t[5]=(short)f2bf(x1.y); t[6]=(short)f2bf(x1.z); t[7]=(short)f2bf(x1.w);
    a[ks] = t;
  }
  f32x4 acc[8];
#pragma unroll
  for (int ct = 0; ct < 8; ++ct) acc[ct] = f32x4{0.f,0.f,0.f,0.f};
#pragma unroll
  for (int ct = 0; ct < 8; ++ct){
    const int n = ct*16 + c16;
#pragma unroll
    for (int ks = 0; ks < NKS; ++ks){
      const bf16x8 b = *reinterpret_cast<const bf16x8*>(
          wlds + ((n << SH) + (((32*ks + 8*g) << 1) ^ ((n & 7) << 4))));
      acc[ct] = mfma16x16x32(a[ks], b, acc[ct]);
    }
  }
#pragma unroll
  for (int ct = 0; ct < 8; ++ct){
    const float bsv = bias[ct*16 + c16];
#pragma unroll
    for (int r = 0; r < 4; ++r){
      const float v = acc[ct][r] + bsv;
      const unsigned short hv = f2bf(v);
      const int row = 16*wave + 4*g + r;
      int off;
      if (VT) off = (ct << 11) + (c16 << 7) + (((row << 1)) ^ ((c16 & 7) << 4));
      else    off = (row << 8) + ((((ct*16 + c16) << 1)) ^ ((row & 7) << 4));
      *reinterpret_cast<unsigned short*>(outstage + off) = hv;
    }
  }
}

__global__ __launch_bounds__(256, 2) void proj_kernel(
    const float* __restrict__ qq, const float* __restrict__ kkin, const float* __restrict__ vvin,
    const float* __restrict__ b_q, const float* __restrict__ b_k, const float* __restrict__ b_v,
    const unsigned short* __restrict__ wsu,
    unsigned short* __restrict__ qs, unsigned short* __restrict__ ksg, unsigned short* __restrict__ vsg)
{
  __shared__ char smem[81920];       // [0,64K) weights, [64K,80K) outstage
  const int tid = threadIdx.x;
  const int wave = tid >> 6, lane = tid & 63;
  const int g = lane >> 4, c16 = lane & 15;
  const bool isK = blockIdx.x >= 256;
  char* outstage = smem + 65536;

  // stage weights once: qv-blocks take WT_q+WT_v (64KB at wsu byte 0), k-blocks WT_k (64KB at byte 65536)
  const char* wsrc = reinterpret_cast<const char*>(wsu) + (isK ? 65536 : 0);
#pragma unroll
  for (int i = 0; i < 16; ++i){
    const int off = (wave*16 + i) * 1024;
    gload_lds16(wsrc + off + lane*16, smem + off);
  }
  __syncthreads();

  const int w0 = (isK ? (blockIdx.x - 256) : blockIdx.x) * 16;
  for (int wl = 0; wl < 16; ++wl){
    const int win = w0 + wl;
    const int bb = win >> 10, wy = (win >> 5) & 31, wx = win & 31;
    const long winbase = (long)bb * 65536 + (long)wy * 2048 + wx * 8;

    if (!isK){
      // ---- q ----
      proj_one<128,false>(qq, b_q, smem, outstage, winbase, wave, lane, g, c16);
      asm volatile("s_waitcnt lgkmcnt(0)" ::: "memory");
      {
        char* dst = reinterpret_cast<char*>(qs) + (size_t)win * 16384 + wave*4096;
        const char* srcs = outstage + wave*4096;
#pragma unroll
        for (int i = 0; i < 4; ++i){
          const uint4 d = *reinterpret_cast<const uint4*>(srcs + i*1024 + lane*16);
          *reinterpret_cast<uint4*>(dst + i*1024 + lane*16) = d;
        }
      }
      __syncthreads();
      // ---- v (transposed layout; scattered across waves -> barrier then coop writeout) ----
      proj_one<128,true>(vvin, b_v, smem + 32768, outstage, winbase, wave, lane, g, c16);
      __syncthreads();
      {
        char* dst = reinterpret_cast<char*>(vsg) + (size_t)win * 16384;
#pragma unroll
        for (int i = 0; i < 4; ++i){
          const uint4 d = *reinterpret_cast<const uint4*>(outstage + tid*16 + i*4096);
          *reinterpret_cast<uint4*>(dst + tid*16 + i*4096) = d;
        }
      }
      __syncthreads();
    } else {
      // ---- k ----
      proj_one<256,false>(kkin, b_k, smem, outstage, winbase, wave, lane, g, c16);
      asm volatile("s_waitcnt lgkmcnt(0)" ::: "memory");
      {
        char* dst = reinterpret_cast<char*>(ksg) + (size_t)win * 16384 + wave*4096;
        const char* srcs = outstage + wave*4096;
#pragma unroll
        for (int i = 0; i < 4; ++i){
          const uint4 d = *reinterpret_cast<const uint4*>(srcs + i*1024 + lane*16);
          *reinterpret_cast<uint4*>(dst + i*1024 + lane*16) = d;
        }
      }
      __syncthreads();
    }
  }
}

// =================== K2: attention + o-projection ===========
__global__ __launch_bounds__(256, 2) void attn_kernel(
    const unsigned short* __restrict__ qs, const unsigned short* __restrict__ ksg,
    const unsigned short* __restrict__ vsg, const unsigned short* __restrict__ wsu,
    const float* __restrict__ b_o, float* __restrict__ out)
{
  __shared__ char smem[57344];   // qp 16K | kp 16K | vt 16K | P 8K ; y(hi/lo) reuses [0,32K)
  const int tid = threadIdx.x;
  const int wave = tid >> 6, lane = tid & 63;
  const int g = lane >> 4, c16 = lane & 15;

  const unsigned short* WT_oh = wsu + 65536;
  const unsigned short* WT_ol = wsu + 81920;
  const float* bias_exp = reinterpret_cast<const float*>(wsu + 98304);

  // o-proj weights in registers: wave owns out-channels ct = 2*wave + cti
  bf16x8 bh[2][4], bl[2][4];
  float bov[2];
#pragma unroll
  for (int cti = 0; cti < 2; ++cti){
    const int n = (2*wave + cti)*16 + c16;
    bov[cti] = b_o[n];
#pragma unroll
    for (int ks = 0; ks < 4; ++ks){
      bh[cti][ks] = *reinterpret_cast<const bf16x8*>(WT_oh + n*128 + 32*ks + 8*g);
      bl[cti][ks] = *reinterpret_cast<const bf16x8*>(WT_ol + n*128 + 32*ks + 8*g);
    }
  }

  const int pbase = P_BASE + wave * 2048;
  for (int wl = 0; wl < 8; ++wl){
    const int win = blockIdx.x*8 + wl;
    const int bb = win >> 10, wy = (win >> 5) & 31, wx = win & 31;
    const long winbase = (long)bb * 65536 + (long)wy * 2048 + wx * 8;

    // ---- stage q,k,vt (48KB) via global_load_lds (layouts already swizzled in ws) ----
    {
      const char* srcs[3] = {
        reinterpret_cast<const char*>(qs)  + (size_t)win * 16384,
        reinterpret_cast<const char*>(ksg) + (size_t)win * 16384,
        reinterpret_cast<const char*>(vsg) + (size_t)win * 16384 };
#pragma unroll
      for (int rg = 0; rg < 3; ++rg){
#pragma unroll
        for (int i2 = 0; i2 < 4; ++i2){
          const int off = (wave*4 + i2) * 1024;
          gload_lds16(srcs[rg] + off + lane*16, smem + rg*16384 + off);
        }
      }
    }
    __syncthreads();

    // ---- phase B: scores -> softmax -> PV (identical math to verified round-1) ----
    float yreg[32];
#pragma unroll
    for (int h = 0; h < 8; ++h){
      bf16x8 aq = {0,0,0,0,0,0,0,0};
      if (g < 2){
        const int row = 16*wave + c16;
        aq = *reinterpret_cast<const bf16x8*>(smem + QP_BASE +
              (((row << 8) + ((h*16 + 8*g) << 1)) ^ ((row & 7) << 4)));
      }
      f32x4 s[4];
#pragma unroll
      for (int kt = 0; kt < 4; ++kt){
        bf16x8 bk8 = {0,0,0,0,0,0,0,0};
        if (g < 2){
          const int row = kt*16 + c16;
          bk8 = *reinterpret_cast<const bf16x8*>(smem + KP_BASE +
                (((row << 8) + ((h*16 + 8*g) << 1)) ^ ((row & 7) << 4)));
        }
        s[kt] = mfma16x16x32(aq, bk8, f32x4{0.f,0.f,0.f,0.f});
      }
      float p[4][4], rcp[4];
#pragma unroll
      for (int r = 0; r < 4; ++r){
        const int qv = 16*wave + 4*g + r;
        const float* brow = bias_exp + (h*64 + qv)*64 + c16;
        const float s0 = s[0][r]*0.25f + brow[0];
        const float s1 = s[1][r]*0.25f + brow[16];
        const float s2 = s[2][r]*0.25f + brow[32];
        const float s3 = s[3][r]*0.25f + brow[48];
        float m = fmaxf(fmaxf(s0, s1), fmaxf(s2, s3));
        m = fmaxf(m, __shfl_xor(m, 1));
        m = fmaxf(m, __shfl_xor(m, 2));
        m = fmaxf(m, __shfl_xor(m, 4));
        m = fmaxf(m, __shfl_xor(m, 8));
        const float p0 = __expf(s0 - m), p1 = __expf(s1 - m);
        const float p2 = __expf(s2 - m), p3 = __expf(s3 - m);
        float sum = p0 + p1 + p2 + p3;
        sum += __shfl_xor(sum, 1);
        sum += __shfl_xor(sum, 2);
        sum += __shfl_xor(sum, 4);
        sum += __shfl_xor(sum, 8);
        rcp[r] = 1.0f / sum;
        p[0][r]=p0; p[1][r]=p1; p[2][r]=p2; p[3][r]=p3;
      }
#pragma unroll
      for (int kt = 0; kt < 4; ++kt)
#pragma unroll
        for (int r = 0; r < 4; ++r){
          const int qloc = 4*g + r;
          *reinterpret_cast<unsigned short*>(smem + pbase +
              (((qloc << 7) + ((kt*16 + c16) << 1)) ^ ((qloc & 7) << 4))) = f2bf(p[kt][r]);
        }
      f32x4 y = {0.f,0.f,0.f,0.f};
#pragma unroll
      for (int ks = 0; ks < 2; ++ks){
        const bf16x8 ap = *reinterpret_cast<const bf16x8*>(smem + pbase +
            (((c16 << 7) + ((32*ks + 8*g) << 1)) ^ ((c16 & 7) << 4)));
        const bf16x8 bv8 = *reinterpret_cast<const bf16x8*>(smem + VT_BASE +
            (((h << 11) + (c16 << 7) + ((32*ks + 8*g) << 1)) ^ ((c16 & 7) << 4)));
        y = mfma16x16x32(ap, bv8, y);
      }
#pragma unroll
      for (int r = 0; r < 4; ++r) yreg[h*4 + r] = y[r] * rcp[r];
    }

    // ---- y (hi/lo bf16) into dead q/k LDS ----
    __syncthreads();
#pragma unroll
    for (int h2 = 0; h2 < 8; ++h2)
#pragma unroll
      for (int r = 0; r < 4; ++r){
        const int row = 16*wave + 4*g + r;
        const int ch = h2*16 + c16;
        const float v = yreg[h2*4 + r];
        const unsigned short hv = f2bf(v);
        const unsigned short lv = f2bf(v - bf2f(hv));
        const int byte = (row << 8) + (((ch << 1)) ^ ((row & 7) << 4));
        *reinterpret_cast<unsigned short*>(smem + QP_BASE + byte) = hv;
        *reinterpret_cast<unsigned short*>(smem + KP_BASE + byte) = lv;
      }
    __syncthreads();

    // ---- phase C: o-projection, wave ct-split, weights in registers ----
#pragma unroll
    for (int rt = 0; rt < 4; ++rt){
      const int row2 = rt*16 + c16;
      bf16x8 ah[4], al[4];
#pragma unroll
      for (int ks = 0; ks < 4; ++ks){
        const int byte = (row2 << 8) + ((((32*ks + 8*g) << 1)) ^ ((row2 & 7) << 4));
        ah[ks] = *reinterpret_cast<const bf16x8*>(smem + QP_BASE + byte);
        al[ks] = *reinterpret_cast<const bf16x8*>(smem + KP_BASE + byte);
      }
#pragma unroll
      for (int cti = 0; cti < 2; ++cti){
        f32x4 acc = {0.f,0.f,0.f,0.f};
#pragma unroll
        for (int ks = 0; ks < 4; ++ks){
          acc = mfma16x16x32(ah[ks], bh[cti][ks], acc);
          acc = mfma16x16x32(al[ks], bh[cti][ks], acc);
          acc = mfma16x16x32(ah[ks], bl[cti][ks], acc);
        }
        const int ch = (2*wave + cti)*16 + c16;
#pragma unroll
        for (int r = 0; r < 4; ++r){
          const int R = rt*16 + 4*g + r;
          const long tok = winbase + (long)(R >> 3)*256 + (R & 7);
          out[tok*128 + ch] = acc[r] + bov[cti];
        }
      }
    }
    __syncthreads();   // before next window's staging overwrites q/k/vt
  }
}

// =================== fallback: round-1 fused kernel (used if ws is too small) ===========
__global__ __launch_bounds__(256, 2) void fused_win_attn(
    const float* __restrict__ qq, const float* __restrict__ kkin, const float* __restrict__ vvin,
    const float* __restrict__ b_q, const float* __restrict__ b_k, const float* __restrict__ b_v,
    const float* __restrict__ b_o, const unsigned short* __restrict__ wsu,
    float* __restrict__ out)
{
  __shared__ char smem[57344];
  const int tid = threadIdx.x;
  const int wave = tid >> 6, lane = tid & 63;
  const int g = lane >> 4, c16 = lane & 15;
  const int wi = blockIdx.x;
  const int bb = wi >> 10, wy = (wi >> 5) & 31, wx = wi & 31;
  const long winbase = (long)bb * 65536 + (long)wy * 2048 + wx * 8;

  const unsigned short* WT_q  = wsu;
  const unsigned short* WT_v  = wsu + 16384;
  const unsigned short* WT_k  = wsu + 32768;
  const unsigned short* WT_oh = wsu + 65536;
  const unsigned short* WT_ol = wsu + 81920;
  const float* bias_exp = reinterpret_cast<const float*>(wsu + 98304);

  // Phase A (linear weights from global)
  {
    const float* Xs[3] = {qq, kkin, vvin};
    const unsigned short* Ws[3] = {WT_q, WT_k, WT_v};
    const float* Bs[3] = {b_q, b_k, b_v};
#pragma unroll
    for (int ph = 0; ph < 3; ++ph){
      const int KC = (ph == 1) ? 256 : 128;
      const int rA = 16*wave + c16;
      const float* xrow = Xs[ph] + (winbase + (long)(rA >> 3) * 256 + (rA & 7)) * KC;
      bf16x8 a[8];
      for (int ks = 0; ks < KC/32; ++ks){
        const float4* p = reinterpret_cast<const float4*>(xrow + 32*ks + 8*g);
        const float4 x0 = p[0], x1 = p[1];
        bf16x8 t;
        t[0]=(short)f2bf(x0.x); t[1]=(short)f2bf(x0.y); t[2]=(short)f2bf(x0.z); t[3]=(short)f2bf(x0.w);
        t[4]=(short)f2bf(x1.x); t[5]=(short)f2bf(x1.y); t[6]=(short)f2bf(x1.z); t[7]=(short)f2bf(x1.w);
        a[ks] = t;
      }
      for (int ct = 0; ct < 8; ++ct){
        f32x4 acc = {0.f,0.f,0.f,0.f};
        const unsigned short* wrow = Ws[ph] + (ct*16 + c16) * KC + 8*g;
        for (int ks = 0; ks < KC/32; ++ks)
          acc = mfma16x16x32(a[ks], *reinterpret_cast<const bf16x8*>(wrow + 32*ks), acc);
        const float bsv = Bs[ph][ct*16 + c16];
        for (int r = 0; r < 4; ++r){
          const float v = acc[r] + bsv;
          const unsigned short hv = f2bf(v);
          const int row = 16*wave + 4*g + r;
          int off;
          if (ph == 0)      off = QP_BASE + (((row << 8) + ((ct*16 + c16) << 1)) ^ ((row & 7) << 4));
          else if (ph == 1) off = KP_BASE + (((row << 8) + ((ct*16 + c16) << 1)) ^ ((row & 7) << 4));
          else              off = VT_BASE + (((ct << 11) + (c16 << 7) + (row << 1)) ^ ((c16 & 7) << 4));
          *reinterpret_cast<unsigned short*>(smem + off) = hv;
        }
      }
    }
  }
  __syncthreads();

  float yreg[32];
  const int pbase = P_BASE + wave * 2048;
#pragma unroll
  for (int h = 0; h < 8; ++h){
    bf16x8 aq = {0,0,0,0,0,0,0,0};
    if (g < 2){
      const int row = 16*wave + c16;
      aq = *reinterpret_cast<const bf16x8*>(smem + QP_BASE +
            (((row << 8) + ((h*16 + 8*g) << 1)) ^ ((row & 7) << 4)));
    }
    f32x4 s[4];
#pragma unroll
    for (int kt = 0; kt < 4; ++kt){
      bf16x8 bk8 = {0,0,0,0,0,0,0,0};
      if (g < 2){
        const int row = kt*16 + c16;
        bk8 = *reinterpret_cast<const bf16x8*>(smem + KP_BASE +
              (((row << 8) + ((h*16 + 8*g) << 1)) ^ ((row & 7) << 4)));
      }
      s[kt] = mfma16x16x32(aq, bk8, f32x4{0.f,0.f,0.f,0.f});
    }
    float p[4][4], rcp[4];
#pragma unroll
    for (int r = 0; r < 4; ++r){
      const int qv = 16*wave + 4*g + r;
      const float* brow = bias_exp + (h*64 + qv)*64 + c16;
      const float s0 = s[0][r]*0.25f + brow[0];
      const float s1 = s[1][r]*0.25f + brow[16];
      const float s2 = s[2][r]*0.25f + brow[32];
      const float s3 = s[3][r]*0.25f + brow[48];
      float m = fmaxf(fmaxf(s0, s1), fmaxf(s2, s3));
      m = fmaxf(m, __shfl_xor(m, 1));
      m = fmaxf(m, __shfl_xor(m, 2));
      m = fmaxf(m, __shfl_xor(m, 4));
      m = fmaxf(m, __shfl_xor(m, 8));
      const float p0 = __expf(s0 - m), p1 = __expf(s1 - m);
      const float p2 = __expf(s2 - m), p3 = __expf(s3 - m);
      float sum = p0 + p1 + p2 + p3;
      sum += __shfl_xor(sum, 1);
      sum += __shfl_xor(sum, 2);
      sum += __shfl_xor(sum, 4);
      sum += __shfl_xor(sum, 8);
      rcp[r] = 1.0f / sum;
      p[0][r]=p0; p[1][r]=p1; p[2][r]=p2; p[3][r]=p3;
    }
#pragma unroll
    for (int kt = 0; kt < 4; ++kt)
#pragma unroll
      for (int r = 0; r < 4; ++r){
        const int qloc = 4*g + r;
        *reinterpret_cast<unsigned short*>(smem + pbase +
            (((qloc << 7) + ((kt*16 + c16) << 1)) ^ ((qloc & 7) << 4))) = f2bf(p[kt][r]);
      }
    f32x4 y = {0.f,0.f,0.f,0.f};
#pragma unroll
    for (int ks = 0; ks < 2; ++ks){
      const bf16x8 ap = *reinterpret_cast<const bf16x8*>(smem + pbase +
          (((c16 << 7) + ((32*ks + 8*g) << 1)) ^ ((c16 & 7) << 4)));
      const bf16x8 bv8 = *reinterpret_cast<const bf16x8*>(smem + VT_BASE +
          (((h << 11) + (c16 << 7) + ((32*ks + 8*g) << 1)) ^ ((c16 & 7) << 4)));
      y = mfma16x16x32(ap, bv8, y);
    }
#pragma unroll
    for (int r = 0; r < 4; ++r) yreg[h*4 + r] = y[r] * rcp[r];
  }

  __syncthreads();
  const int ybase = wave * 8192;
#pragma unroll
  for (int h2 = 0; h2 < 8; ++h2)
#pragma unroll
    for (int r = 0; r < 4; ++r){
      const int row = 4*g + r;
      const int ch = h2*16 + c16;
      *reinterpret_cast<float*>(smem + ybase +
          (((row << 9) + (ch << 2)) ^ ((row & 7) << 4))) = yreg[h2*4 + r];
    }
  bf16x8 ahi[4], alo[4];
#pragma unroll
  for (int ks = 0; ks < 4; ++ks){
    const int k0 = 32*ks + 8*g;
    const f32x4 v0 = *reinterpret_cast<const f32x4*>(smem + ybase +
        (((c16 << 9) + (k0 << 2)) ^ ((c16 & 7) << 4)));
    const f32x4 v1 = *reinterpret_cast<const f32x4*>(smem + ybase +
        (((c16 << 9) + ((k0 + 4) << 2)) ^ ((c16 & 7) << 4)));
    bf16x8 h8, l8;
#pragma unroll
    for (int j = 0; j < 4; ++j){
      const unsigned short hh = f2bf(v0[j]);
      h8[j] = (short)hh; l8[j] = (short)f2bf(v0[j] - bf2f(hh));
    }
#pragma unroll
    for (int j = 0; j < 4; ++j){
      const unsigned short hh = f2bf(v1[j]);
      h8[4+j] = (short)hh; l8[4+j] = (short)f2bf(v1[j] - bf2f(hh));
    }
    ahi[ks] = h8; alo[ks] = l8;
  }
#pragma unroll
  for (int ct = 0; ct < 8; ++ct){
    f32x4 acc = {0.f,0.f,0.f,0.f};
    const unsigned short* whrow = WT_oh + (ct*16 + c16)*128 + 8*g;
    const unsigned short* wlrow = WT_ol + (ct*16 + c16)*128 + 8*g;
#pragma unroll
    for (int ks = 0; ks < 4; ++ks){
      const bf16x8 bhx = *reinterpret_cast<const bf16x8*>(whrow + 32*ks);
      const bf16x8 blx = *reinterpret_cast<const bf16x8*>(wlrow + 32*ks);
      acc = mfma16x16x32(ahi[ks], bhx, acc);
      acc = mfma16x16x32(alo[ks], bhx, acc);
      acc = mfma16x16x32(ahi[ks], blx, acc);
    }
    const float bov = b_o[ct*16 + c16];
#pragma unroll
    for (int r = 0; r < 4; ++r){
      const int R = 16*wave + 4*g + r;
      const long tok = winbase + (long)(R >> 3)*256 + (R & 7);
      out[tok*128 + ct*16 + c16] = acc[r] + bov;
    }
  }
}

extern "C" void kernel_launch(void* const* d_in, const int* in_sizes, int n_in,
                              void* d_out, int out_size, void* d_ws, size_t ws_size,
                              hipStream_t stream)
{
  (void)in_sizes; (void)n_in; (void)out_size;
  const float* qq   = (const float*)d_in[0];
  const float* kk   = (const float*)d_in[1];
  const float* vv   = (const float*)d_in[2];
  const float* w_q  = (const float*)d_in[3];
  const float* b_q  = (const float*)d_in[4];
  const float* w_k  = (const float*)d_in[5];
  const float* b_k  = (const float*)d_in[6];
  const float* w_v  = (const float*)d_in[7];
  const float* b_v  = (const float*)d_in[8];
  const float* w_o  = (const float*)d_in[9];
  const float* b_o  = (const float*)d_in[10];
  const float* btab = (const float*)d_in[11];
  unsigned short* wsu = (unsigned short*)d_ws;
  float* out = (float*)d_out;

  const bool big = ws_size >= 201850880ULL;   // 320KB prep + 3 x 64MB staging
  prep_kernel<<<448, 256, 0, stream>>>(w_q, w_k, w_v, w_o, btab, wsu, big ? 1 : 0);
  if (big){
    unsigned short* qsp = wsu + 262144;            // byte offset 512KB
    unsigned short* ksp = qsp + 33554432;          // +64MB
    unsigned short* vsp = ksp + 33554432;          // +64MB
    proj_kernel<<<512, 256, 0, stream>>>(qq, kk, vv, b_q, b_k, b_v, wsu, qsp, ksp, vsp);
    attn_kernel<<<512, 256, 0, stream>>>(qsp, ksp, vsp, wsu, b_o, out);
  } else {
    fused_win_attn<<<4096, 256, 0, stream>>>(qq, kk, vv, b_q, b_k, b_v, b_o, wsu, out);
  }
}

// Round 3
// 266.943 us; speedup vs baseline: 2.6436x; 2.6436x over previous
//
#include <hip/hip_runtime.h>
#include <cstdint>

typedef float f32x4  __attribute__((ext_vector_type(4)));
typedef float f32x16 __attribute__((ext_vector_type(16)));
typedef short bf16x8 __attribute__((ext_vector_type(8)));
typedef unsigned int u32;

#define QP_BASE 0
#define KP_BASE 16384
#define VT_BASE 32768

__device__ __forceinline__ unsigned short f2bf(float f){
  union { float f; uint32_t u; } v; v.f = f;
  uint32_t u = v.u;
  return (unsigned short)((u + 0x7FFFu + ((u >> 16) & 1u)) >> 16);  // RNE
}
__device__ __forceinline__ float bf2f(unsigned short h){
  union { uint32_t u; float f; } v; v.u = ((uint32_t)h) << 16;
  return v.f;
}
__device__ __forceinline__ u32 pack2bf(float a, float b){
  return (u32)f2bf(a) | ((u32)f2bf(b) << 16);
}
__device__ __forceinline__ f32x4 mfma16(bf16x8 a, bf16x8 b, f32x4 c){
  return __builtin_amdgcn_mfma_f32_16x16x32_bf16(a, b, c, 0, 0, 0);
}
__device__ __forceinline__ f32x16 mfma32(bf16x8 a, bf16x8 b, f32x16 c){
  return __builtin_amdgcn_mfma_f32_32x32x16_bf16(a, b, c, 0, 0, 0);
}
__device__ __forceinline__ void gload_lds16(const void* gsrc, void* ldst){
  __builtin_amdgcn_global_load_lds(
    (const __attribute__((address_space(1))) unsigned int*)gsrc,
    (__attribute__((address_space(3))) unsigned int*)ldst, 16, 0, 0);
}

// ---------------- prep ----------------
// wsu layout (shorts): WT_q [0,16384) | WT_v [16384,32768) | WT_k [32768,65536)
//   WT_oh [65536,81920) | WT_ol [81920,98304) | bias_t u32[16384] at short 98304 (byte 196608)
// bias_t layout: [h][qh][t][h5][i(8)][q(32)] as u32 = (bf16 for reg 2i) | (bf16 for reg 2i+1)<<16
//   reg r of score tile t <-> key = t*32 + 4*h5 + (r&3) + 8*(r>>2);  q_glob = qh*32 + q
__global__ void prep_kernel(const float* __restrict__ wq, const float* __restrict__ wk,
                            const float* __restrict__ wv, const float* __restrict__ wo,
                            const float* __restrict__ btab, unsigned short* __restrict__ wsu)
{
  const int idx = blockIdx.x * 256 + threadIdx.x;
  if (idx < 16384){                          // WT_q[n][k] = wq[k][n], swizzled
    const int n = idx >> 7, k = idx & 127;
    wsu[n*128 + (k ^ ((n & 7) << 3))] = f2bf(wq[k*128 + n]);
  } else if (idx < 32768){                   // WT_v
    const int i = idx - 16384, n = i >> 7, k = i & 127;
    wsu[16384 + n*128 + (k ^ ((n & 7) << 3))] = f2bf(wv[k*128 + n]);
  } else if (idx < 65536){                   // WT_k (K=256)
    const int i = idx - 32768, n = i >> 8, k = i & 255;
    wsu[32768 + n*256 + (k ^ ((n & 7) << 3))] = f2bf(wk[k*128 + n]);
  } else if (idx < 81920){                   // WT_o hi/lo (linear [n][k])
    const int i = idx - 65536, n = i >> 7, k = i & 127;
    const float f = wo[k*128 + n];
    const unsigned short hv = f2bf(f);
    wsu[65536 + n*128 + k] = hv;
    wsu[81920 + n*128 + k] = f2bf(f - bf2f(hv));
  } else if (idx < 98304){                   // bias_t
    const int i = idx - 81920;
    const int q  = i & 31;
    const int ib = (i >> 5) & 7;
    const int h5 = (i >> 8) & 1;
    const int t  = (i >> 9) & 1;
    const int qh = (i >> 10) & 1;
    const int h  = (i >> 11);
    const int qg = qh*32 + q;
    const int qi = qg >> 3, qj = qg & 7;
    u32 wv2 = 0;
#pragma unroll
    for (int e = 0; e < 2; ++e){
      const int r = 2*ib + e;
      const int key = t*32 + 4*h5 + (r & 3) + 8*(r >> 2);
      const int ki = key >> 3, kj = key & 7;
      const int rel = (qi - ki + 7) * 15 + (qj - kj + 7);
      wv2 |= ((u32)f2bf(btab[rel*8 + h])) << (16*e);
    }
    reinterpret_cast<u32*>(wsu + 98304)[i] = wv2;
  }
}

// =================== K1: projection GEMMs -> ws (pre-swizzled per-window chunks) ===========
// qs/ks chunk (16KB/window): byte = (row<<8) + ((ch*2) ^ ((row&15)<<4))
// vs chunk (16KB/window):    byte = (h<<11) + (ch16<<7) + ((key*2) ^ ((ch16&7)<<4))
template<int KC, bool VT>
__device__ __forceinline__ void proj_one(const float* __restrict__ X, const float* __restrict__ bias,
    const char* wlds, char* outstage, long winbase, int wave, int lane, int g, int c16)
{
  constexpr int NKS = KC / 32;
  constexpr int SH  = (KC == 128) ? 8 : 9;
  const int rA = 16*wave + c16;
  const float* xrow = X + (winbase + (long)(rA >> 3) * 256 + (rA & 7)) * KC;
  bf16x8 a[NKS];
#pragma unroll
  for (int ks = 0; ks < NKS; ++ks){
    const float4* p = reinterpret_cast<const float4*>(xrow + 32*ks + 8*g);
    const float4 x0 = p[0], x1 = p[1];
    bf16x8 t;
    t[0]=(short)f2bf(x0.x); t[1]=(short)f2bf(x0.y); t[2]=(short)f2bf(x0.z); t[3]=(short)f2bf(x0.w);
    t[4]=(short)f2bf(x1.x); t[5]=(short)f2bf(x1.y); t[6]=(short)f2bf(x1.z); t[7]=(short)f2bf(x1.w);
    a[ks] = t;
  }
  f32x4 acc[8];
#pragma unroll
  for (int ct = 0; ct < 8; ++ct) acc[ct] = f32x4{0.f,0.f,0.f,0.f};
#pragma unroll
  for (int ct = 0; ct < 8; ++ct){
    const int n = ct*16 + c16;
#pragma unroll
    for (int ks = 0; ks < NKS; ++ks){
      const bf16x8 b = *reinterpret_cast<const bf16x8*>(
          wlds + ((n << SH) + (((32*ks + 8*g) << 1) ^ ((n & 7) << 4))));
      acc[ct] = mfma16(a[ks], b, acc[ct]);
    }
  }
#pragma unroll
  for (int ct = 0; ct < 8; ++ct){
    const float bsv = bias[ct*16 + c16];
#pragma unroll
    for (int r = 0; r < 4; ++r){
      const float v = acc[ct][r] + bsv;
      const unsigned short hv = f2bf(v);
      const int row = 16*wave + 4*g + r;
      int off;
      if (VT) off = (ct << 11) + (c16 << 7) + ((row << 1) ^ ((c16 & 7) << 4));
      else    off = (row << 8) + (((ct*16 + c16) << 1) ^ ((row & 15) << 4));
      *reinterpret_cast<unsigned short*>(outstage + off) = hv;
    }
  }
}

__global__ __launch_bounds__(256, 2) void proj_kernel(
    const float* __restrict__ qq, const float* __restrict__ kkin, const float* __restrict__ vvin,
    const float* __restrict__ b_q, const float* __restrict__ b_k, const float* __restrict__ b_v,
    const unsigned short* __restrict__ wsu,
    unsigned short* __restrict__ qs, unsigned short* __restrict__ ksg, unsigned short* __restrict__ vsg)
{
  __shared__ char smem[81920];       // [0,64K) weights, [64K,80K) outstage
  const int tid = threadIdx.x;
  const int wave = tid >> 6, lane = tid & 63;
  const int g = lane >> 4, c16 = lane & 15;
  const bool isK = blockIdx.x >= 256;
  char* outstage = smem + 65536;

  const char* wsrc = reinterpret_cast<const char*>(wsu) + (isK ? 65536 : 0);
#pragma unroll
  for (int i = 0; i < 16; ++i){
    const int off = (wave*16 + i) * 1024;
    gload_lds16(wsrc + off + lane*16, smem + off);
  }
  __syncthreads();

  const int w0 = (isK ? (blockIdx.x - 256) : blockIdx.x) * 16;
  for (int wl = 0; wl < 16; ++wl){
    const int win = w0 + wl;
    const int bb = win >> 10, wy = (win >> 5) & 31, wx = win & 31;
    const long winbase = (long)bb * 65536 + (long)wy * 2048 + wx * 8;

    if (!isK){
      proj_one<128,false>(qq, b_q, smem, outstage, winbase, wave, lane, g, c16);
      asm volatile("s_waitcnt lgkmcnt(0)" ::: "memory");
      {
        char* dst = reinterpret_cast<char*>(qs) + (size_t)win * 16384 + wave*4096;
        const char* srcs = outstage + wave*4096;
#pragma unroll
        for (int i = 0; i < 4; ++i){
          const uint4 d = *reinterpret_cast<const uint4*>(srcs + i*1024 + lane*16);
          *reinterpret_cast<uint4*>(dst + i*1024 + lane*16) = d;
        }
      }
      __syncthreads();
      proj_one<128,true>(vvin, b_v, smem + 32768, outstage, winbase, wave, lane, g, c16);
      __syncthreads();
      {
        char* dst = reinterpret_cast<char*>(vsg) + (size_t)win * 16384;
#pragma unroll
        for (int i = 0; i < 4; ++i){
          const uint4 d = *reinterpret_cast<const uint4*>(outstage + tid*16 + i*4096);
          *reinterpret_cast<uint4*>(dst + tid*16 + i*4096) = d;
        }
      }
      __syncthreads();
    } else {
      proj_one<256,false>(kkin, b_k, smem, outstage, winbase, wave, lane, g, c16);
      asm volatile("s_waitcnt lgkmcnt(0)" ::: "memory");
      {
        char* dst = reinterpret_cast<char*>(ksg) + (size_t)win * 16384 + wave*4096;
        const char* srcs = outstage + wave*4096;
#pragma unroll
        for (int i = 0; i < 4; ++i){
          const uint4 d = *reinterpret_cast<const uint4*>(srcs + i*1024 + lane*16);
          *reinterpret_cast<uint4*>(dst + i*1024 + lane*16) = d;
        }
      }
      __syncthreads();
    }
  }
}

// =================== K2: attention + o-projection, 512 threads / window ===========
// wave w: qh = w&1 (q rows qh*32..+32), head pair hp = w>>1 (heads 2hp, 2hp+1)
// S^T = mfma32(A=K[key][ch], B=Q^T) -> lane owns q = qh*32 + (l&31), keys: bit2(key)==l>>5
__global__ __launch_bounds__(512, 4) void attn_kernel(
    const unsigned short* __restrict__ qs, const unsigned short* __restrict__ ksg,
    const unsigned short* __restrict__ vsg, const unsigned short* __restrict__ wsu,
    const float* __restrict__ b_o, float* __restrict__ out)
{
  __shared__ char smem[49152];   // q 16K | k 16K | vt 16K ; after: yh [0,16K), yl [16K,32K)
  const int tid = threadIdx.x;
  const int wave = tid >> 6, lane = tid & 63;
  const int l31 = lane & 31, h5 = lane >> 5;
  const int qh = wave & 1, hp = wave >> 1;

  const int win = blockIdx.x;
  const int bb = win >> 10, wy = (win >> 5) & 31, wx = win & 31;
  const long winbase = (long)bb * 65536 + (long)wy * 2048 + wx * 8;

  const u32* bias_u = reinterpret_cast<const u32*>(wsu + 98304);

  // ---- stage q,k,vt (48KB) ----
  {
    const char* srcs[3] = {
      reinterpret_cast<const char*>(qs)  + (size_t)win * 16384,
      reinterpret_cast<const char*>(ksg) + (size_t)win * 16384,
      reinterpret_cast<const char*>(vsg) + (size_t)win * 16384 };
#pragma unroll
    for (int rg = 0; rg < 3; ++rg)
#pragma unroll
      for (int j = 0; j < 2; ++j){
        const int off = j*8192 + tid*16;
        gload_lds16(srcs[rg] + off, smem + rg*16384 + off);
      }
  }
  __syncthreads();

  // ---- per-head: scores^T -> softmax (in-reg) -> PV ----
  f32x16 y[2];
#pragma unroll
  for (int hh = 0; hh < 2; ++hh){
    const int h = 2*hp + hh;
    const int chb = (h*16 + 8*h5) * 2;          // byte offset of head-ch slice in a row
    bf16x8 kf0, kf1, qf;
    { const int row = l31;
      kf0 = *reinterpret_cast<const bf16x8*>(smem + KP_BASE + (row<<8) + (chb ^ ((row&15)<<4))); }
    { const int row = 32 + l31;
      kf1 = *reinterpret_cast<const bf16x8*>(smem + KP_BASE + (row<<8) + (chb ^ ((row&15)<<4))); }
    { const int row = qh*32 + l31;
      qf  = *reinterpret_cast<const bf16x8*>(smem + QP_BASE + (row<<8) + (chb ^ ((row&15)<<4))); }
    f32x16 z = {};
    f32x16 s0 = mfma32(kf0, qf, z);
    f32x16 s1 = mfma32(kf1, qf, z);

    // bias + scale
    const u32* bb2 = bias_u + ((((h*2 + qh)*2 + 0)*2 + h5)*8)*32 + l31;
    float t[32];
#pragma unroll
    for (int i = 0; i < 8; ++i){
      const u32 w0 = bb2[i*32];
      const u32 w1 = bb2[512 + i*32];
      t[2*i]     = fmaf(s0[2*i],   0.25f, bf2f((unsigned short)(w0 & 0xffff)));
      t[2*i+1]   = fmaf(s0[2*i+1], 0.25f, bf2f((unsigned short)(w0 >> 16)));
      t[16+2*i]  = fmaf(s1[2*i],   0.25f, bf2f((unsigned short)(w1 & 0xffff)));
      t[17+2*i]  = fmaf(s1[2*i+1], 0.25f, bf2f((unsigned short)(w1 >> 16)));
    }
    float m = t[0];
#pragma unroll
    for (int r = 1; r < 32; ++r) m = fmaxf(m, t[r]);
    m = fmaxf(m, __shfl_xor(m, 32));
    float sum = 0.f;
#pragma unroll
    for (int r = 0; r < 32; ++r){ t[r] = __expf(t[r] - m); sum += t[r]; }
    sum += __shfl_xor(sum, 32);
    const float rs = 1.0f / sum;
    u32 pk0[8], pk1[8];
#pragma unroll
    for (int i = 0; i < 8; ++i){
      pk0[i] = pack2bf(t[2*i]*rs,    t[2*i+1]*rs);
      pk1[i] = pack2bf(t[16+2*i]*rs, t[17+2*i]*rs);
    }

    // PV: 4x mfma32, A from regs (half-swap via shfl), B from vt
    f32x16 yy = {};
    const int chr = l31 & 15;
#pragma unroll
    for (int m4 = 0; m4 < 4; ++m4){
      const int jb = 4*(m4 & 1);
      const u32 a0 = (m4 < 2) ? pk0[jb]   : pk1[jb];
      const u32 a1 = (m4 < 2) ? pk0[jb+1] : pk1[jb+1];
      const u32 a2 = (m4 < 2) ? pk0[jb+2] : pk1[jb+2];
      const u32 a3 = (m4 < 2) ? pk0[jb+3] : pk1[jb+3];
      const u32 s0w = (u32)__shfl_xor((int)a0, 32);
      const u32 s1w = (u32)__shfl_xor((int)a1, 32);
      const u32 s2w = (u32)__shfl_xor((int)a2, 32);
      const u32 s3w = (u32)__shfl_xor((int)a3, 32);
      union { u32 w[4]; bf16x8 v; } afu;
      afu.w[0] = h5 ? s2w : a0;
      afu.w[1] = h5 ? s3w : a1;
      afu.w[2] = h5 ? a2  : s0w;
      afu.w[3] = h5 ? a3  : s1w;
      const int kb = 32*m4 + 16*h5;             // key*2 byte offset
      const bf16x8 bv = *reinterpret_cast<const bf16x8*>(
          smem + VT_BASE + (h<<11) + (chr<<7) + (kb ^ ((chr & 7) << 4)));
      yy = mfma32(afu.v, bv, yy);
    }
    y[hh] = yy;
  }
  __syncthreads();   // everyone done reading q/k/vt

  // ---- y -> LDS hi/lo planes (lanes with l31<16 hold real ch) ----
  if (l31 < 16){
#pragma unroll
    for (int hh = 0; hh < 2; ++hh){
      const int ch = (2*hp + hh)*16 + l31;
#pragma unroll
      for (int r = 0; r < 16; ++r){
        const int row = qh*32 + (r & 3) + 8*(r >> 2) + 4*h5;
        const float v = y[hh][r];
        const unsigned short hv = f2bf(v);
        const unsigned short lv = f2bf(v - bf2f(hv));
        const int byte = (row << 8) + ((ch << 1) ^ ((row & 15) << 4));
        *reinterpret_cast<unsigned short*>(smem + byte)         = hv;
        *reinterpret_cast<unsigned short*>(smem + 16384 + byte) = lv;
      }
    }
  }
  __syncthreads();

  // ---- o-projection: wave owns out-channel block ct = wave ----
  {
    const int g = lane >> 4, c16 = lane & 15;
    const int ct = wave;
    const unsigned short* WT_oh = wsu + 65536;
    const unsigned short* WT_ol = wsu + 81920;
    bf16x8 bh[4], bl[4];
#pragma unroll
    for (int ks = 0; ks < 4; ++ks){
      bh[ks] = *reinterpret_cast<const bf16x8*>(WT_oh + (ct*16+c16)*128 + 32*ks + 8*g);
      bl[ks] = *reinterpret_cast<const bf16x8*>(WT_ol + (ct*16+c16)*128 + 32*ks + 8*g);
    }
    const float bov = b_o[ct*16 + c16];
#pragma unroll
    for (int rt = 0; rt < 4; ++rt){
      const int row2 = rt*16 + c16;
      bf16x8 ah[4], al[4];
#pragma unroll
      for (int ks = 0; ks < 4; ++ks){
        const int byte = (row2 << 8) + ((64*ks + 16*g) ^ ((row2 & 15) << 4));
        ah[ks] = *reinterpret_cast<const bf16x8*>(smem + byte);
        al[ks] = *reinterpret_cast<const bf16x8*>(smem + 16384 + byte);
      }
      f32x4 acc = {};
#pragma unroll
      for (int ks = 0; ks < 4; ++ks){
        acc = mfma16(ah[ks], bh[ks], acc);
        acc = mfma16(al[ks], bh[ks], acc);
        acc = mfma16(ah[ks], bl[ks], acc);
      }
#pragma unroll
      for (int r = 0; r < 4; ++r){
        const int R = rt*16 + 4*g + r;
        const long tok = winbase + (long)(R >> 3)*256 + (R & 7);
        out[tok*128 + ct*16 + c16] = acc[r] + bov;
      }
    }
  }
}

extern "C" void kernel_launch(void* const* d_in, const int* in_sizes, int n_in,
                              void* d_out, int out_size, void* d_ws, size_t ws_size,
                              hipStream_t stream)
{
  (void)in_sizes; (void)n_in; (void)out_size; (void)ws_size;
  const float* qq   = (const float*)d_in[0];
  const float* kk   = (const float*)d_in[1];
  const float* vv   = (const float*)d_in[2];
  const float* w_q  = (const float*)d_in[3];
  const float* b_q  = (const float*)d_in[4];
  const float* w_k  = (const float*)d_in[5];
  const float* b_k  = (const float*)d_in[6];
  const float* w_v  = (const float*)d_in[7];
  const float* b_v  = (const float*)d_in[8];
  const float* w_o  = (const float*)d_in[9];
  const float* b_o  = (const float*)d_in[10];
  const float* btab = (const float*)d_in[11];
  unsigned short* wsu = (unsigned short*)d_ws;
  float* out = (float*)d_out;

  unsigned short* qsp = wsu + 131072;            // byte 262144
  unsigned short* ksp = qsp + 33554432;          // +64MB
  unsigned short* vsp = ksp + 33554432;          // +64MB

  prep_kernel<<<384, 256, 0, stream>>>(w_q, w_k, w_v, w_o, btab, wsu);
  proj_kernel<<<512, 256, 0, stream>>>(qq, kk, vv, b_q, b_k, b_v, wsu, qsp, ksp, vsp);
  attn_kernel<<<4096, 512, 0, stream>>>(qsp, ksp, vsp, wsu, b_o, out);
}